// Round 1
// baseline (64.605 us; speedup 1.0000x reference)
//
#include <hip/hip_runtime.h>
#include <math.h>

// Problem constants (from reference)
#define BATCH 128
#define LL    4096
#define DIM   64
#define EPS   1e-3f

// d_ws layout (floats):
//  [0    .. 1536) : CW[br][d][8] = {W0..W4 (BN-folded conv taps), Bf (folded bias), f_w[d], pad}
//  [1536 .. 1792) : MOD[d][4]    = {A_d, C_d, MD_d0, MD_d1}   (folded mp+BN, md*BN-scale)
//  [1792 .. 1795) : FB[3]        = f1_b, f2_b, fI_b
//  [1795 .. 1797) : D0, D1       = folded md bias+BN
// total 1797 floats = 7188 bytes (ws_size must be >= this; harness scratch is plenty)

__device__ __forceinline__ float elu_f(float z) {
    return z > 0.0f ? z : (__expf(z) - 1.0f);
}

__global__ void enc_fold(
    const float* __restrict__ cw0, const float* __restrict__ cb0, const float* __restrict__ cg0,
    const float* __restrict__ cbe0, const float* __restrict__ cm0, const float* __restrict__ cv0,
    const float* __restrict__ cw1, const float* __restrict__ cb1, const float* __restrict__ cg1,
    const float* __restrict__ cbe1, const float* __restrict__ cm1, const float* __restrict__ cv1,
    const float* __restrict__ cw2, const float* __restrict__ cb2, const float* __restrict__ cg2,
    const float* __restrict__ cbe2, const float* __restrict__ cm2, const float* __restrict__ cv2,
    const float* __restrict__ f0w, const float* __restrict__ f0b,
    const float* __restrict__ f1w, const float* __restrict__ f1b,
    const float* __restrict__ f2w, const float* __restrict__ f2b,
    const float* __restrict__ mpw, const float* __restrict__ mpb, const float* __restrict__ mpg,
    const float* __restrict__ mpbe, const float* __restrict__ mpm, const float* __restrict__ mpv,
    const float* __restrict__ mdw, const float* __restrict__ mdb, const float* __restrict__ mdg,
    const float* __restrict__ mdbe, const float* __restrict__ mdm, const float* __restrict__ mdv,
    float* __restrict__ W)
{
    const int t = threadIdx.x;
    if (t < 192) {
        const int br = t >> 6;
        const int d  = t & 63;
        const float* cw  = (br == 0) ? cw0  : (br == 1) ? cw1  : cw2;
        const float* cb  = (br == 0) ? cb0  : (br == 1) ? cb1  : cb2;
        const float* cg  = (br == 0) ? cg0  : (br == 1) ? cg1  : cg2;
        const float* cbe = (br == 0) ? cbe0 : (br == 1) ? cbe1 : cbe2;
        const float* cm  = (br == 0) ? cm0  : (br == 1) ? cm1  : cm2;
        const float* cv  = (br == 0) ? cv0  : (br == 1) ? cv1  : cv2;
        const float* fw  = (br == 0) ? f0w  : (br == 1) ? f1w  : f2w;
        const float s = cg[d] / sqrtf(cv[d] + EPS);
        float* o = W + t * 8;
        #pragma unroll
        for (int k = 0; k < 5; ++k) o[k] = cw[k * 64 + d] * s;
        o[5] = (cb[d] - cm[d]) * s + cbe[d];
        o[6] = fw[d];          // (64,1) dense weight
        o[7] = 0.0f;
    } else {
        const int d = t - 192;
        const float smp = mpg[d] / sqrtf(mpv[d] + EPS);
        const float A = mpw[d] * smp;
        const float C = (mpb[d] - mpm[d]) * smp + mpbe[d];
        const float s0 = mdg[0] / sqrtf(mdv[0] + EPS);
        const float s1 = mdg[1] / sqrtf(mdv[1] + EPS);
        float* o = W + 1536 + d * 4;
        o[0] = A;
        o[1] = C;
        o[2] = mdw[d * 2 + 0] * s0;
        o[3] = mdw[d * 2 + 1] * s1;
        if (d == 0) {
            W[1792] = f0b[0];
            W[1793] = f1b[0];
            W[1794] = f2b[0];
            W[1795] = (mdb[0] - mdm[0]) * s0 + mdbe[0];
            W[1796] = (mdb[1] - mdm[1]) * s1 + mdbe[1];
        }
    }
}

// 1024 blocks x 256 threads; each block: one batch row tile of 512 positions,
// each thread: 2 adjacent positions, all 3 branches + modulation fused.
__global__ __launch_bounds__(256) void enc_main(
    const float* __restrict__ x, const int* __restrict__ perm,
    const float* __restrict__ W, float* __restrict__ out)
{
    __shared__ float xs[LL];
    const int t    = threadIdx.x;
    const int b    = blockIdx.x >> 3;
    const int tile = blockIdx.x & 7;

    // stage full transformed row into LDS (needed for interleaver gathers)
    const float4* xr4 = (const float4*)(x + (size_t)b * LL);
    float4* xs4 = (float4*)xs;
    #pragma unroll
    for (int i = 0; i < 4; ++i) {
        float4 v = xr4[t + 256 * i];
        v.x = 2.0f * v.x - 1.0f;
        v.y = 2.0f * v.y - 1.0f;
        v.z = 2.0f * v.z - 1.0f;
        v.w = 2.0f * v.w - 1.0f;
        xs4[t + 256 * i] = v;
    }
    __syncthreads();

    const int l0 = tile * 512 + t * 2;

    // windows for positions l0 and l0+1 (circular)
    float xw[6], xi[6];
    const int* prow = perm + (size_t)b * LL;
    #pragma unroll
    for (int k = 0; k < 6; ++k) {
        const int idx = (l0 + k - 2) & (LL - 1);
        xw[k] = xs[idx];
        xi[k] = xs[prow[idx]];
    }

    // ---- stage 1: three conv branches -> e[branch][pos] ----
    float e00, e01, e10, e11, e20, e21;
    {
        const float fb0 = W[1792], fb1 = W[1793], fb2 = W[1794];
        e00 = e01 = fb0;
        e10 = e11 = fb1;
        e20 = e21 = fb2;
    }
    #pragma unroll 4
    for (int d = 0; d < 64; ++d) {
        const float* w0 = W + d * 8;
        const float* w1 = W + 512 + d * 8;
        const float* w2 = W + 1024 + d * 8;
        float h;
        h = fmaf(w0[0], xw[0], fmaf(w0[1], xw[1], fmaf(w0[2], xw[2], fmaf(w0[3], xw[3], fmaf(w0[4], xw[4], w0[5])))));
        e00 = fmaf(w0[6], elu_f(h), e00);
        h = fmaf(w0[0], xw[1], fmaf(w0[1], xw[2], fmaf(w0[2], xw[3], fmaf(w0[3], xw[4], fmaf(w0[4], xw[5], w0[5])))));
        e01 = fmaf(w0[6], elu_f(h), e01);

        h = fmaf(w1[0], xw[0], fmaf(w1[1], xw[1], fmaf(w1[2], xw[2], fmaf(w1[3], xw[3], fmaf(w1[4], xw[4], w1[5])))));
        e10 = fmaf(w1[6], elu_f(h), e10);
        h = fmaf(w1[0], xw[1], fmaf(w1[1], xw[2], fmaf(w1[2], xw[3], fmaf(w1[3], xw[4], fmaf(w1[4], xw[5], w1[5])))));
        e11 = fmaf(w1[6], elu_f(h), e11);

        h = fmaf(w2[0], xi[0], fmaf(w2[1], xi[1], fmaf(w2[2], xi[2], fmaf(w2[3], xi[3], fmaf(w2[4], xi[4], w2[5])))));
        e20 = fmaf(w2[6], elu_f(h), e20);
        h = fmaf(w2[0], xi[1], fmaf(w2[1], xi[2], fmaf(w2[2], xi[3], fmaf(w2[3], xi[4], fmaf(w2[4], xi[5], w2[5])))));
        e21 = fmaf(w2[6], elu_f(h), e21);
    }

    // ---- stage 2: modulation (pointwise in e) ----
    // output order within a thread: pos0:(br0 c0,c1)(br1)(br2), pos1:(...)
    const float ev0 = e00, ev1 = e10, ev2 = e20, ev3 = e01, ev4 = e11, ev5 = e21;
    float c[12];
    {
        const float D0 = W[1795], D1 = W[1796];
        #pragma unroll
        for (int j = 0; j < 6; ++j) { c[2 * j] = D0; c[2 * j + 1] = D1; }
    }
    #pragma unroll 4
    for (int d = 0; d < 64; ++d) {
        const float* md = W + 1536 + d * 4;
        const float A = md[0], C = md[1], m0 = md[2], m1 = md[3];
        float mo;
        mo = elu_f(fmaf(A, ev0, C)); c[0]  = fmaf(m0, mo, c[0]);  c[1]  = fmaf(m1, mo, c[1]);
        mo = elu_f(fmaf(A, ev1, C)); c[2]  = fmaf(m0, mo, c[2]);  c[3]  = fmaf(m1, mo, c[3]);
        mo = elu_f(fmaf(A, ev2, C)); c[4]  = fmaf(m0, mo, c[4]);  c[5]  = fmaf(m1, mo, c[5]);
        mo = elu_f(fmaf(A, ev3, C)); c[6]  = fmaf(m0, mo, c[6]);  c[7]  = fmaf(m1, mo, c[7]);
        mo = elu_f(fmaf(A, ev4, C)); c[8]  = fmaf(m0, mo, c[8]);  c[9]  = fmaf(m1, mo, c[9]);
        mo = elu_f(fmaf(A, ev5, C)); c[10] = fmaf(m0, mo, c[10]); c[11] = fmaf(m1, mo, c[11]);
    }

    // 12 contiguous floats per thread -> 3x dwordx4, fully coalesced
    float4* o4 = (float4*)(out + (size_t)b * 24576 + (size_t)l0 * 6);
    o4[0] = make_float4(c[0], c[1], c[2],  c[3]);
    o4[1] = make_float4(c[4], c[5], c[6],  c[7]);
    o4[2] = make_float4(c[8], c[9], c[10], c[11]);
}

extern "C" void kernel_launch(void* const* d_in, const int* in_sizes, int n_in,
                              void* d_out, int out_size, void* d_ws, size_t ws_size,
                              hipStream_t stream) {
    const float* x    = (const float*)d_in[0];
    const int*   perm = (const int*)d_in[1];
    float* W = (float*)d_ws;

    enc_fold<<<1, 256, 0, stream>>>(
        (const float*)d_in[2],  (const float*)d_in[3],  (const float*)d_in[4],
        (const float*)d_in[5],  (const float*)d_in[6],  (const float*)d_in[7],
        (const float*)d_in[8],  (const float*)d_in[9],  (const float*)d_in[10],
        (const float*)d_in[11], (const float*)d_in[12], (const float*)d_in[13],
        (const float*)d_in[14], (const float*)d_in[15], (const float*)d_in[16],
        (const float*)d_in[17], (const float*)d_in[18], (const float*)d_in[19],
        (const float*)d_in[20], (const float*)d_in[21],
        (const float*)d_in[22], (const float*)d_in[23],
        (const float*)d_in[24], (const float*)d_in[25],
        (const float*)d_in[26], (const float*)d_in[27], (const float*)d_in[28],
        (const float*)d_in[29], (const float*)d_in[30], (const float*)d_in[31],
        (const float*)d_in[32], (const float*)d_in[33], (const float*)d_in[34],
        (const float*)d_in[35], (const float*)d_in[36], (const float*)d_in[37],
        W);

    enc_main<<<BATCH * (LL / 512), 256, 0, stream>>>(x, perm, W, (float*)d_out);
}